// Round 10
// baseline (329.267 us; speedup 1.0000x reference)
//
#include <hip/hip_runtime.h>
#include <math.h>

#define NLAYERS 2
#define HID 128
#define FFND 256
#define NH 4
#define SEQL 2048
#define HD 32
#define HDV 64
#define VD 256
#define NBATCH 2
#define MROWS (NBATCH*SEQL)   // 4096
#define NCAT 768              // Q(128) | K(128) | V(256) | G(256)
#define NCHUNK 32             // SEQL / 64

// gammas: 1 - exp(linspace(log(1/32), log(1/512), 4))
#define LG32   (-3.4657359028f)
#define DLT    (-0.9241962407f)
__device__ __forceinline__ float lgamma_h(int h) {
  return logf(1.f - expf(LG32 + DLT * (float)h));
}

// ---------------------------------------------------------------------------
// Pack per-head weights into one (HID x 768) matrix per layer (proven R6).
// ---------------------------------------------------------------------------
__global__ __launch_bounds__(256) void pack_w_kernel(
    const float* __restrict__ WQ, const float* __restrict__ WK,
    const float* __restrict__ WV, const float* __restrict__ WG,
    float* __restrict__ Wcat)
{
  int idx = blockIdx.x * 256 + threadIdx.x;
  if (idx >= NLAYERS * HID * NCAT) return;
  int l = idx / (HID * NCAT);
  int r = idx - l * (HID * NCAT);
  int k = r / NCAT;
  int n = r - k * NCAT;
  float v;
  if (n < 128)      { int h = n >> 5, e = n & 31;            v = WQ[(((l*NH+h)*HID)+k)*HD  + e]; }
  else if (n < 256) { int m = n-128; int h = m>>5, e = m&31; v = WK[(((l*NH+h)*HID)+k)*HD  + e]; }
  else if (n < 512) { int m = n-256; int h = m>>6, e = m&63; v = WV[(((l*NH+h)*HID)+k)*HDV + e]; }
  else              { v = WG[(l*HID + k)*VD + (n-512)]; }
  Wcat[idx] = v;
}

// ---------------------------------------------------------------------------
// LayerNorm rows of 128; one wave per row, 4 rows per block (proven R2).
// ---------------------------------------------------------------------------
__global__ __launch_bounds__(256) void ln_rows_kernel(
    const float* __restrict__ X, const float* __restrict__ g,
    const float* __restrict__ b, float* __restrict__ O)
{
  int wid = threadIdx.x >> 6, lane = threadIdx.x & 63;
  int row = blockIdx.x * 4 + wid;
  const float* x = X + (size_t)row * HID;
  float v0 = x[lane], v1 = x[lane + 64];
  float s = v0 + v1;
  #pragma unroll
  for (int o = 32; o; o >>= 1) s += __shfl_xor(s, o);
  float mu = s * (1.f/128.f);
  float d0 = v0 - mu, d1 = v1 - mu;
  float q = d0*d0 + d1*d1;
  #pragma unroll
  for (int o = 32; o; o >>= 1) q += __shfl_xor(q, o);
  float rs = rsqrtf(q * (1.f/128.f) + 1e-5f);
  O[(size_t)row*HID + lane]      = d0 * rs * g[lane]      + b[lane];
  O[(size_t)row*HID + lane + 64] = d1 * rs * g[lane + 64] + b[lane + 64];
}

// ---------------------------------------------------------------------------
// QKVG projection + inline xPos. Tile 32M x 256N, 512 threads, micro 4x4.
// A (LN'd H) read from GLOBAL with wave-uniform addresses (ty = wave id).
// B (Wcat) staged in LDS, k-tile 16, register-prefetched. Grid (128,3)=384.
// ---------------------------------------------------------------------------
__global__ __launch_bounds__(512) void gemm_qkvg(
    const float* __restrict__ H, const float* __restrict__ Wcat,
    float* __restrict__ C)
{
  __shared__ float Bs[16][260];
  int tid = threadIdx.x;
  int tx = tid & 63, ty = tid >> 6;        // cols 4*tx, rows 4*ty (wave-uniform)
  int rb = blockIdx.x * 32, nb = blockIdx.y * 256;

  float4 pre[2];
  #pragma unroll
  for (int it = 0; it < 2; it++) {
    int f = it*512 + tid;                   // f4 index
    int kk = f >> 6, c4 = f & 63;
    pre[it] = *(const float4*)(Wcat + (size_t)kk*NCAT + nb + 4*c4);
  }

  float acc[4][4];
  #pragma unroll
  for (int i=0;i<4;i++)
    #pragma unroll
    for (int j=0;j<4;j++) acc[i][j] = 0.f;

  for (int kt = 0; kt < 8; kt++) {
    int ks = kt * 16;
    #pragma unroll
    for (int it = 0; it < 2; it++) {
      int f = it*512 + tid;
      int kk = f >> 6, c4 = f & 63;
      *(float4*)&Bs[kk][4*c4] = pre[it];
    }
    __syncthreads();
    if (kt + 1 < 8) {
      #pragma unroll
      for (int it = 0; it < 2; it++) {
        int f = it*512 + tid;
        int kk = f >> 6, c4 = f & 63;
        pre[it] = *(const float4*)(Wcat + (size_t)(ks+16+kk)*NCAT + nb + 4*c4);
      }
    }
    #pragma unroll
    for (int k0 = 0; k0 < 16; k0 += 4) {
      float4 av[4];
      #pragma unroll
      for (int i=0;i<4;i++)   // wave-uniform global reads (L1/SMEM broadcast)
        av[i] = *(const float4*)(H + (size_t)(rb + 4*ty + i)*HID + ks + k0);
      float4 bv[4];
      #pragma unroll
      for (int kq=0;kq<4;kq++)
        bv[kq] = *(const float4*)&Bs[k0+kq][4*tx];
      #pragma unroll
      for (int i=0;i<4;i++) {
        float a4[4] = {av[i].x, av[i].y, av[i].z, av[i].w};
        #pragma unroll
        for (int kq=0;kq<4;kq++) {
          acc[i][0] = fmaf(a4[kq], bv[kq].x, acc[i][0]);
          acc[i][1] = fmaf(a4[kq], bv[kq].y, acc[i][1]);
          acc[i][2] = fmaf(a4[kq], bv[kq].z, acc[i][2]);
          acc[i][3] = fmaf(a4[kq], bv[kq].w, acc[i][3]);
        }
      }
    }
    __syncthreads();
  }

  // epilogue: inline-trig xPos on cols < 256 (verified R8), then store
  int col0 = nb + 4*tx;
  #pragma unroll
  for (int i=0;i<4;i++) {
    int row = rb + 4*ty + i;
    float o[4] = {acc[i][0], acc[i][1], acc[i][2], acc[i][3]};
    if (col0 < 256) {
      bool isK = (col0 >= 128);
      float sgn = isK ? -1.f : 1.f;
      float s = (float)(row & (SEQL - 1));
      #pragma unroll
      for (int p = 0; p < 2; p++) {
        float fi   = (float)(((col0 & 31) >> 1) + p);
        float invf = exp2f(fi * -0.83048202372f);
        float sv   = (2.f*fi + 12.8f) * (1.f/44.8f);
        float sc   = exp2f(log2f(sv) * (1.f/512.f) * sgn * s);
        float ang  = s * invf;
        float sn = sinf(ang) * sc, cs = cosf(ang) * sc;
        float x1 = o[2*p], x2 = o[2*p+1];
        o[2*p]   = x1*cs - x2*sn;
        o[2*p+1] = x2*cs + x1*sn;
      }
    }
    *(float4*)(C + (size_t)row*NCAT + col0) = *(float4*)o;
  }
}

// ---------------------------------------------------------------------------
// Retention pass A: per (b,h,chunk) decayed KV summary (proven R6).
// ---------------------------------------------------------------------------
__global__ __launch_bounds__(512) void ret_kv_kernel(
    const float* __restrict__ QKVG, float* __restrict__ Asum)
{
  int bh = blockIdx.x >> 5;
  int c  = blockIdx.x & 31;
  int b = bh >> 2, h = bh & 3;
  float lg = lgamma_h(h);

  __shared__ float Ks[64][36];
  __shared__ float Vs[64][68];
  __shared__ float wt[64];

  int tid = threadIdx.x;
  int c0 = c * 64;
  const float* base = QKVG + (size_t)(b * SEQL) * NCAT;

  {
    int row = tid >> 3, eq = tid & 7;
    *(float4*)&Ks[row][4*eq] =
        *(const float4*)(base + (size_t)(c0+row)*NCAT + 128 + h*32 + 4*eq);
  }
  #pragma unroll
  for (int it = 0; it < 2; it++) {
    int idx = it*512 + tid;
    int row = idx >> 4, vq = idx & 15;
    *(float4*)&Vs[row][4*vq] =
        *(const float4*)(base + (size_t)(c0+row)*NCAT + 256 + h*64 + 4*vq);
  }
  if (tid < 64) wt[tid] = __expf(lg * (float)(64 - tid));
  __syncthreads();

  int e = tid >> 4, v4 = (tid & 15) * 4;
  float a0[4] = {0,0,0,0};
  #pragma unroll 8
  for (int t = 0; t < 64; t++) {
    float kw = Ks[t][e] * wt[t];
    float4 v0 = *(const float4*)&Vs[t][v4];
    a0[0] = fmaf(kw, v0.x, a0[0]); a0[1] = fmaf(kw, v0.y, a0[1]);
    a0[2] = fmaf(kw, v0.z, a0[2]); a0[3] = fmaf(kw, v0.w, a0[3]);
  }
  *(float4*)(Asum + ((size_t)(bh*NCHUNK + c))*2048 + e*64 + v4) = *(float4*)a0;
}

// ---------------------------------------------------------------------------
// Retention pass C + GroupNorm + SiLU gate (proven R6/R8).
// ---------------------------------------------------------------------------
__global__ __launch_bounds__(512) void ret_out_kernel(
    const float* __restrict__ QKVG, const float* __restrict__ Asum,
    const float* __restrict__ gn_g, const float* __restrict__ gn_b,
    float* __restrict__ Gated)
{
  int bh = blockIdx.x >> 5;
  int c  = blockIdx.x & 31;
  int b = bh >> 2, h = bh & 3;
  float lg = lgamma_h(h);
  float g64 = __expf(lg * 64.f);

  __shared__ float Qs[64][36];
  __shared__ float Ks[64][36];
  __shared__ float Vs[64][68];
  __shared__ float Ss[64][68];
  __shared__ float Sc[32][68];

  int tid = threadIdx.x;
  int tx2 = tid & 31, ty2 = tid >> 5;
  int c0 = c * 64;
  const float* base = QKVG + (size_t)(b * SEQL) * NCAT;

  {
    int row = tid >> 3, eq = tid & 7;
    *(float4*)&Qs[row][4*eq] =
        *(const float4*)(base + (size_t)(c0+row)*NCAT + h*32 + 4*eq);
    int esw = (4*eq) ^ (4*((row >> 2) & 7));
    *(float4*)&Ks[row][esw] =
        *(const float4*)(base + (size_t)(c0+row)*NCAT + 128 + h*32 + 4*eq);
  }
  #pragma unroll
  for (int it = 0; it < 2; it++) {
    int idx = it*512 + tid;
    int row = idx >> 4, vq = idx & 15;
    *(float4*)&Vs[row][4*vq] =
        *(const float4*)(base + (size_t)(c0+row)*NCAT + 256 + h*64 + 4*vq);
  }

  {
    int e = tid >> 4, v4 = (tid & 15) * 4;
    float s0[4] = {0,0,0,0};
    float w = 1.f;
    const float* ab = Asum + ((size_t)bh*NCHUNK)*2048 + e*64 + v4;
    for (int cp = c-1; cp >= 0; --cp) {
      const float* ap = ab + (size_t)cp*2048;
      float4 x0 = *(const float4*)ap;
      s0[0] = fmaf(w, x0.x, s0[0]); s0[1] = fmaf(w, x0.y, s0[1]);
      s0[2] = fmaf(w, x0.z, s0[2]); s0[3] = fmaf(w, x0.w, s0[3]);
      w *= g64;
    }
    *(float4*)&Sc[e][v4] = *(float4*)s0;
  }
  __syncthreads();

  float sacc[4][2];
  #pragma unroll
  for (int i=0;i<4;i++) { sacc[i][0]=0.f; sacc[i][1]=0.f; }
  #pragma unroll
  for (int e = 0; e < 32; e += 4) {
    float qv[4][4], kv[2][4];
    #pragma unroll
    for (int i=0;i<4;i++)
      *(float4*)qv[i] = *(const float4*)&Qs[4*ty2+i][e];
    #pragma unroll
    for (int j=0;j<2;j++) {
      int kr = 2*tx2 + j;
      *(float4*)kv[j] = *(const float4*)&Ks[kr][e ^ (4*((kr>>2)&7))];
    }
    #pragma unroll
    for (int i=0;i<4;i++)
      #pragma unroll
      for (int j=0;j<2;j++)
        sacc[i][j] = fmaf(qv[i][0], kv[j][0],
                     fmaf(qv[i][1], kv[j][1],
                     fmaf(qv[i][2], kv[j][2],
                     fmaf(qv[i][3], kv[j][3], sacc[i][j]))));
  }
  #pragma unroll
  for (int i=0;i<4;i++) {
    int sl = 4*ty2 + i;
    float o2[2];
    #pragma unroll
    for (int j=0;j<2;j++) {
      int dr = sl - (2*tx2 + j);
      float w = (dr >= 0) ? __expf(lg * (float)dr) : 0.f;
      o2[j] = sacc[i][j] * w;
    }
    *(float2*)&Ss[sl][2*tx2] = *(float2*)o2;
  }

  float acc[4][2];
  #pragma unroll
  for (int i=0;i<4;i++) { acc[i][0]=0.f; acc[i][1]=0.f; }
  #pragma unroll
  for (int e = 0; e < 32; e += 4) {
    float qv[4][4], sv[4][2];
    #pragma unroll
    for (int i=0;i<4;i++)
      *(float4*)qv[i] = *(const float4*)&Qs[4*ty2+i][e];
    #pragma unroll
    for (int m=0;m<4;m++)
      *(float2*)sv[m] = *(const float2*)&Sc[e+m][2*tx2];
    #pragma unroll
    for (int i=0;i<4;i++)
      #pragma unroll
      for (int j=0;j<2;j++)
        acc[i][j] = fmaf(qv[i][0], sv[0][j],
                    fmaf(qv[i][1], sv[1][j],
                    fmaf(qv[i][2], sv[2][j],
                    fmaf(qv[i][3], sv[3][j], acc[i][j]))));
  }
  #pragma unroll
  for (int i=0;i<4;i++) {
    float gr = __expf(lg * (float)(4*ty2 + i));
    acc[i][0] *= gr; acc[i][1] *= gr;
  }
  __syncthreads();

  #pragma unroll
  for (int t = 0; t < 64; t += 4) {
    float sv[4][4], vv[4][2];
    #pragma unroll
    for (int i=0;i<4;i++)
      *(float4*)sv[i] = *(const float4*)&Ss[4*ty2+i][t];
    #pragma unroll
    for (int m=0;m<4;m++)
      *(float2*)vv[m] = *(const float2*)&Vs[t+m][2*tx2];
    #pragma unroll
    for (int i=0;i<4;i++)
      #pragma unroll
      for (int j=0;j<2;j++)
        acc[i][j] = fmaf(sv[i][0], vv[0][j],
                    fmaf(sv[i][1], vv[1][j],
                    fmaf(sv[i][2], vv[2][j],
                    fmaf(sv[i][3], vv[3][j], acc[i][j]))));
  }

  #pragma unroll
  for (int i=0;i<4;i++) {
    float s1 = acc[i][0] + acc[i][1];
    #pragma unroll
    for (int o = 16; o; o >>= 1) s1 += __shfl_xor(s1, o);
    float mu = s1 * (1.f/64.f);
    float q = 0.f;
    #pragma unroll
    for (int j=0;j<2;j++) { float d = acc[i][j] - mu; q += d*d; }
    #pragma unroll
    for (int o = 16; o; o >>= 1) q += __shfl_xor(q, o);
    float rs = rsqrtf(q * (1.f/64.f) + 1e-5f);
    int row = b*SEQL + c0 + 4*ty2 + i;
    float2 g2 = *(const float2*)(QKVG + (size_t)row*NCAT + 512 + h*64 + 2*tx2);
    float gv[2] = {g2.x, g2.y};
    float o2[2];
    #pragma unroll
    for (int j=0;j<2;j++) {
      int col = h*64 + 2*tx2 + j;
      float yn = (acc[i][j] - mu) * rs * gn_g[col] + gn_b[col];
      float g = gv[j];
      float sig = 1.f / (1.f + __expf(-g));
      o2[j] = g * sig * yn;
    }
    *(float2*)(Gated + (size_t)row*VD + h*64 + 2*tx2) = *(float2*)o2;
  }
}

// ---------------------------------------------------------------------------
// Fused WO + residual + LN2 + FFN1(gelu) + FFN2 + residual.
// 256 blocks x 512 threads, 16-row slabs. A-operands: wave-uniform global
// (Gated) or LDS row-major broadcast (h2s, Ms). B-weights: LDS k-tiles with
// register prefetch. yr residual kept in registers.
// ---------------------------------------------------------------------------
__global__ __launch_bounds__(512) void ffn_chain(
    const float* __restrict__ Gated, const float* __restrict__ WO,
    const float* __restrict__ Xres,
    const float* __restrict__ lng, const float* __restrict__ lnb,
    const float* __restrict__ w1, const float* __restrict__ b1,
    const float* __restrict__ w2, const float* __restrict__ b2,
    float* __restrict__ Out)
{
  __shared__ float WsBuf[32*132];   // WO/FFN2 tiles [32][132]; FFN1 tile [16][260]
  __shared__ float h2s[16][132];
  __shared__ float Ms[16][260];

  int tid = threadIdx.x;
  int rb = blockIdx.x * 16;
  int tx = tid & 63, ty = tid >> 6;        // rows 2ty..2ty+1 (wave-uniform)

  // =============== WO phase: K=256, N=128, micro 2x2 ===============
  float yr[2][2];
  {
    float4 pre[2];
    #pragma unroll
    for (int it = 0; it < 2; it++) {
      int f = it*512 + tid;
      int kk = f >> 5, c4 = f & 31;
      pre[it] = *(const float4*)(WO + (size_t)kk*HID + 4*c4);
    }
    float acc[2][2] = {{0.f,0.f},{0.f,0.f}};
    for (int kt = 0; kt < 8; kt++) {
      int ks = kt * 32;
      #pragma unroll
      for (int it = 0; it < 2; it++) {
        int f = it*512 + tid;
        int kk = f >> 5, c4 = f & 31;
        *(float4*)&WsBuf[kk*132 + 4*c4] = pre[it];
      }
      __syncthreads();
      if (kt + 1 < 8) {
        #pragma unroll
        for (int it = 0; it < 2; it++) {
          int f = it*512 + tid;
          int kk = f >> 5, c4 = f & 31;
          pre[it] = *(const float4*)(WO + (size_t)(ks+32+kk)*HID + 4*c4);
        }
      }
      #pragma unroll
      for (int k0 = 0; k0 < 32; k0 += 4) {
        float4 av[2];
        #pragma unroll
        for (int i=0;i<2;i++)   // wave-uniform global (L1 broadcast)
          av[i] = *(const float4*)(Gated + (size_t)(rb + 2*ty + i)*VD + ks + k0);
        float2 bv[4];
        #pragma unroll
        for (int kq=0;kq<4;kq++)
          bv[kq] = *(const float2*)&WsBuf[(k0+kq)*132 + 2*tx];
        #pragma unroll
        for (int i=0;i<2;i++) {
          float a4[4] = {av[i].x, av[i].y, av[i].z, av[i].w};
          #pragma unroll
          for (int kq=0;kq<4;kq++) {
            acc[i][0] = fmaf(a4[kq], bv[kq].x, acc[i][0]);
            acc[i][1] = fmaf(a4[kq], bv[kq].y, acc[i][1]);
          }
        }
      }
      __syncthreads();
    }
    #pragma unroll
    for (int i=0;i<2;i++) {
      float2 xr = *(const float2*)(Xres + (size_t)(rb + 2*ty + i)*HID + 2*tx);
      yr[i][0] = acc[i][0] + xr.x;
      yr[i][1] = acc[i][1] + xr.y;
    }
  }

  // =============== LN2 (row fully in-wave) -> h2s ===============
  #pragma unroll
  for (int i=0;i<2;i++) {
    float s = yr[i][0] + yr[i][1];
    #pragma unroll
    for (int o = 32; o; o >>= 1) s += __shfl_xor(s, o);
    float mu = s * (1.f/128.f);
    float d0 = yr[i][0]-mu, d1 = yr[i][1]-mu;
    float q = d0*d0 + d1*d1;
    #pragma unroll
    for (int o = 32; o; o >>= 1) q += __shfl_xor(q, o);
    float rs = rsqrtf(q * (1.f/128.f) + 1e-5f);
    float o2[2] = { d0*rs*lng[2*tx+0] + lnb[2*tx+0],
                    d1*rs*lng[2*tx+1] + lnb[2*tx+1] };
    *(float2*)&h2s[2*ty+i][2*tx] = *(float2*)o2;
  }
  __syncthreads();

  // =============== FFN1: K=128, N=256, micro 2x4, gelu -> Ms ===============
  {
    float4 pre[2];
    #pragma unroll
    for (int it = 0; it < 2; it++) {
      int f = it*512 + tid;
      int kk = f >> 6, c4 = f & 63;
      pre[it] = *(const float4*)(w1 + (size_t)kk*FFND + 4*c4);
    }
    float acc[2][4];
    #pragma unroll
    for (int i=0;i<2;i++)
      #pragma unroll
      for (int j=0;j<4;j++) acc[i][j] = 0.f;
    for (int kt = 0; kt < 8; kt++) {
      int ks = kt * 16;
      #pragma unroll
      for (int it = 0; it < 2; it++) {
        int f = it*512 + tid;
        int kk = f >> 6, c4 = f & 63;
        *(float4*)&WsBuf[kk*260 + 4*c4] = pre[it];
      }
      __syncthreads();
      if (kt + 1 < 8) {
        #pragma unroll
        for (int it = 0; it < 2; it++) {
          int f = it*512 + tid;
          int kk = f >> 6, c4 = f & 63;
          pre[it] = *(const float4*)(w1 + (size_t)(ks+16+kk)*FFND + 4*c4);
        }
      }
      #pragma unroll
      for (int k0 = 0; k0 < 16; k0 += 4) {
        float4 av[2];
        #pragma unroll
        for (int i=0;i<2;i++)   // LDS broadcast (ty wave-uniform)
          av[i] = *(const float4*)&h2s[2*ty+i][ks + k0];
        float4 bv[4];
        #pragma unroll
        for (int kq=0;kq<4;kq++)
          bv[kq] = *(const float4*)&WsBuf[(k0+kq)*260 + 4*tx];
        #pragma unroll
        for (int i=0;i<2;i++) {
          float a4[4] = {av[i].x, av[i].y, av[i].z, av[i].w};
          #pragma unroll
          for (int kq=0;kq<4;kq++) {
            acc[i][0] = fmaf(a4[kq], bv[kq].x, acc[i][0]);
            acc[i][1] = fmaf(a4[kq], bv[kq].y, acc[i][1]);
            acc[i][2] = fmaf(a4[kq], bv[kq].z, acc[i][2]);
            acc[i][3] = fmaf(a4[kq], bv[kq].w, acc[i][3]);
          }
        }
      }
      __syncthreads();
    }
    float4 bi = *(const float4*)(b1 + 4*tx);
    float bvi[4] = {bi.x, bi.y, bi.z, bi.w};
    #pragma unroll
    for (int i=0;i<2;i++) {
      float o[4];
      #pragma unroll
      for (int j=0;j<4;j++) {
        float v = acc[i][j] + bvi[j];
        o[j] = 0.5f * v * (1.f + erff(v * 0.70710678118f));
      }
      *(float4*)&Ms[2*ty+i][4*tx] = *(float4*)o;
    }
  }
  __syncthreads();

  // =============== FFN2: K=256, N=128, micro 2x2, +b2 +yr -> Out ===========
  {
    float4 pre[2];
    #pragma unroll
    for (int it = 0; it < 2; it++) {
      int f = it*512 + tid;
      int kk = f >> 5, c4 = f & 31;
      pre[it] = *(const float4*)(w2 + (size_t)kk*HID + 4*c4);
    }
    float acc[2][2] = {{0.f,0.f},{0.f,0.f}};
    for (int kt = 0; kt < 8; kt++) {
      int ks = kt * 32;
      #pragma unroll
      for (int it = 0; it < 2; it++) {
        int f = it*512 + tid;
        int kk = f >> 5, c4 = f & 31;
        *(float4*)&WsBuf[kk*132 + 4*c4] = pre[it];
      }
      __syncthreads();
      if (kt + 1 < 8) {
        #pragma unroll
        for (int it = 0; it < 2; it++) {
          int f = it*512 + tid;
          int kk = f >> 5, c4 = f & 31;
          pre[it] = *(const float4*)(w2 + (size_t)(ks+32+kk)*HID + 4*c4);
        }
      }
      #pragma unroll
      for (int k0 = 0; k0 < 32; k0 += 4) {
        float4 av[2];
        #pragma unroll
        for (int i=0;i<2;i++)
          av[i] = *(const float4*)&Ms[2*ty+i][ks + k0];
        float2 bv[4];
        #pragma unroll
        for (int kq=0;kq<4;kq++)
          bv[kq] = *(const float2*)&WsBuf[(k0+kq)*132 + 2*tx];
        #pragma unroll
        for (int i=0;i<2;i++) {
          float a4[4] = {av[i].x, av[i].y, av[i].z, av[i].w};
          #pragma unroll
          for (int kq=0;kq<4;kq++) {
            acc[i][0] = fmaf(a4[kq], bv[kq].x, acc[i][0]);
            acc[i][1] = fmaf(a4[kq], bv[kq].y, acc[i][1]);
          }
        }
      }
      __syncthreads();
    }
    #pragma unroll
    for (int i=0;i<2;i++) {
      float o2[2] = { acc[i][0] + b2[2*tx+0] + yr[i][0],
                      acc[i][1] + b2[2*tx+1] + yr[i][1] };
      *(float2*)(Out + (size_t)(rb + 2*ty + i)*HID + 2*tx) = *(float2*)o2;
    }
  }
}

// ---------------------------------------------------------------------------
extern "C" void kernel_launch(void* const* d_in, const int* in_sizes, int n_in,
                              void* d_out, int out_size, void* d_ws, size_t ws_size,
                              hipStream_t stream)
{
  (void)in_sizes; (void)n_in; (void)out_size; (void)ws_size;
  const float* x_in  = (const float*)d_in[0];
  const float* ln1_g = (const float*)d_in[1];
  const float* ln1_b = (const float*)d_in[2];
  const float* ln2_g = (const float*)d_in[3];
  const float* ln2_b = (const float*)d_in[4];
  const float* WQ    = (const float*)d_in[5];
  const float* WK    = (const float*)d_in[6];
  const float* WV    = (const float*)d_in[7];
  const float* WG    = (const float*)d_in[8];
  const float* WO    = (const float*)d_in[9];
  const float* gn_g  = (const float*)d_in[10];
  const float* gn_b  = (const float*)d_in[11];
  const float* w1    = (const float*)d_in[12];
  const float* b1    = (const float*)d_in[13];
  const float* w2    = (const float*)d_in[14];
  const float* b2    = (const float*)d_in[15];
  float* out = (float*)d_out;
  float* ws  = (float*)d_ws;

  float* Wcat = ws;                       // 196608
  float* Hbuf = Wcat + 196608;            // 524288
  float* QKVG = Hbuf + 524288;            // 3145728
  float* Asum = QKVG + 3145728;           // 524288
  float* Gt   = Asum + 524288;            // 1048576

  pack_w_kernel<<<768, 256, 0, stream>>>(WQ, WK, WV, WG, Wcat);

  for (int l = 0; l < NLAYERS; l++) {
    const float* xl = (l == 0) ? x_in : out;
    ln_rows_kernel<<<MROWS/4, 256, 0, stream>>>(xl, ln1_g + l*HID, ln1_b + l*HID, Hbuf);
    gemm_qkvg<<<dim3(MROWS/32, 3), 512, 0, stream>>>(Hbuf, Wcat + l*HID*NCAT, QKVG);
    ret_kv_kernel<<<256, 512, 0, stream>>>(QKVG, Asum);
    ret_out_kernel<<<256, 512, 0, stream>>>(QKVG, Asum, gn_g + l*VD, gn_b + l*VD, Gt);
    ffn_chain<<<256, 512, 0, stream>>>(
        Gt, WO + l*VD*HID, xl, ln2_g + l*HID, ln2_b + l*HID,
        w1 + l*HID*FFND, b1 + l*FFND, w2 + l*FFND*HID, b2 + l*HID, out);
  }
}